// Round 9
// baseline (206.169 us; speedup 1.0000x reference)
//
#include <hip/hip_runtime.h>
#include <stdint.h>

#define Bb 2
#define Tt 2048
#define Cc 1024
#define Hh 16
#define HD 64
#define C3 3072

typedef __bf16 bf16x8 __attribute__((ext_vector_type(8)));
typedef float  f32x4  __attribute__((ext_vector_type(4)));
typedef unsigned short u16;
typedef u16 u16x8 __attribute__((ext_vector_type(8)));
typedef u16 u16x4 __attribute__((ext_vector_type(4)));

#define SCALE2 0.18033688f  /* 1/sqrt(64) * log2(e) */

__device__ __forceinline__ u16 f2bf(float f) {
  union { float f; unsigned u; } v; v.f = f;
  return (u16)((v.u + 0x7fffu + ((v.u >> 16) & 1u)) >> 16);  // RNE
}
__device__ __forceinline__ float bf2f(u16 a) {
  union { unsigned u; float f; } v; v.u = ((unsigned)a) << 16; return v.f;
}

// async global->LDS, 16B per lane. LDS dest = wave-uniform base + lane*16.
__device__ __forceinline__ void gl2lds16(const void* g, void* s) {
  __builtin_amdgcn_global_load_lds(
      (__attribute__((address_space(1))) void*)(g),
      (__attribute__((address_space(3))) void*)(s), 16, 0, 0);
}

__device__ __forceinline__ bf16x8 ldb8(const u16* p) {
  return __builtin_bit_cast(bf16x8, *(const u16x8*)p);
}

// counted vmcnt wait: allow N of this wave's VMEM ops to stay in flight.
template <int N>
__device__ __forceinline__ void vmwait() {
  asm volatile("s_waitcnt vmcnt(%0)" :: "n"(N) : "memory");
}
// raw s_barrier (no compiler vmcnt(0) drain); sched_barrier pins motion.
__device__ __forceinline__ void barrier_nodrain() {
  __builtin_amdgcn_s_barrier();
  __builtin_amdgcn_sched_barrier(0);
}

// ---------------- merged prep: cvt_x + w_attn^T + w_proj^T ----------------
__global__ __launch_bounds__(256)
void prep_kernel(const float* __restrict__ x, const float* __restrict__ w_attn,
                 const float* __restrict__ w_proj, u16* __restrict__ xb,
                 u16* __restrict__ wat, u16* __restrict__ wpt) {
  __shared__ u16 tile[64][65];
  const int blk = blockIdx.x;
  const int tid = threadIdx.x;
  if (blk < 4096) {
    int i = blk * 256 + tid;
    float4 v = ((const float4*)x)[i];
    u16x4 o = { f2bf(v.x), f2bf(v.y), f2bf(v.z), f2bf(v.w) };
    ((u16x4*)xb)[i] = o;
    return;
  }
  const float* in; u16* out; int R, C, c0, r0;
  if (blk < 4096 + 768) {
    int t = blk - 4096;
    in = w_attn; out = wat; R = 1024; C = 3072;
    c0 = (t % 48) * 64; r0 = (t / 48) * 64;
  } else {
    int t = blk - 4864;
    in = w_proj; out = wpt; R = 1024; C = 1024;
    c0 = (t & 15) * 64; r0 = (t >> 4) * 64;
  }
  int xx = tid & 63, yy = tid >> 6;
  #pragma unroll
  for (int rr = yy; rr < 64; rr += 4)
    tile[rr][xx] = f2bf(in[(size_t)(r0 + rr) * C + c0 + xx]);
  __syncthreads();
  #pragma unroll
  for (int rr = yy; rr < 64; rr += 4)
    out[(size_t)(c0 + rr) * R + r0 + xx] = tile[xx][rr];
}

// ---------------- bf16 GEMM: C[M][N] = A[M][K] * Bt[N][K]^T + bias ----------------
// R5 version (best measured gemm1: ~35us): 128xBN tile, BK=32, triple-buffered
// LDS, depth-2 prefetch, counted-vmcnt barriers. MODE 1 (BN=128): bf16 out
// ldc=2048 for Q,K; V cols (>=2048) written transposed + kv-permuted into Vt.
template <int MODE, int BN, int MINW>
__global__ __launch_bounds__(256, MINW)
void gemm_bt(const u16* __restrict__ A, const u16* __restrict__ Bt,
             const float* __restrict__ bias, void* __restrict__ Cout,
             u16* __restrict__ Vt, int M, int N, int K) {
  __shared__ u16 As[3][128 * 32];
  __shared__ u16 Bs[3][BN * 32];
  constexpr int JT = BN / 32;
  constexpr int NB = BN / 128 + 1;
  constexpr int L  = 2 + NB;
  const int tid = threadIdx.x;
  const int ln  = tid & 63;
  const int w   = tid >> 6;
  const int wm  = w >> 1, wn = w & 1;
  const int l15 = ln & 15, lq = ln >> 4;
  const int swz2 = (l15 >> 1) & 3;
  const int m0 = blockIdx.y * 128, n0 = blockIdx.x * BN;

  int aoff[2], boff[NB];
  #pragma unroll
  for (int i = 0; i < 2; ++i) {
    int s = i * 256 + tid;
    int row = s >> 2, cg = (s & 3) ^ ((s >> 3) & 3);
    aoff[i] = (m0 + row) * K + cg * 8;
  }
  #pragma unroll
  for (int i = 0; i < NB; ++i) {
    int s = i * 256 + tid;
    int row = s >> 2, cg = (s & 3) ^ ((s >> 3) & 3);
    boff[i] = (n0 + row) * K + cg * 8;
  }

  f32x4 acc[4][JT];
  #pragma unroll
  for (int i = 0; i < 4; ++i)
    #pragma unroll
    for (int j = 0; j < JT; ++j)
      acc[i][j] = (f32x4){0.f, 0.f, 0.f, 0.f};

  const int NK = K >> 5;

  auto STAGE = [&](int buf, int t) {
    const int k0 = t * 32;
    #pragma unroll
    for (int i = 0; i < 2; ++i)
      gl2lds16(A + aoff[i] + k0, (char*)As[buf] + (size_t)(i * 256 + w * 64) * 16);
    #pragma unroll
    for (int i = 0; i < NB; ++i)
      gl2lds16(Bt + boff[i] + k0, (char*)Bs[buf] + (size_t)(i * 256 + w * 64) * 16);
  };

  STAGE(0, 0);
  if (NK > 1) STAGE(1, 1);

  int cur = 0;
  for (int it = 0; it < NK; ++it) {
    if (it + 1 < NK) vmwait<L>(); else vmwait<0>();
    barrier_nodrain();
    if (it + 2 < NK) STAGE(cur == 0 ? 2 : cur - 1, it + 2);
    const u16* AsB = As[cur];
    const u16* BsB = Bs[cur];
    bf16x8 af[4], bfr[JT];
    #pragma unroll
    for (int i = 0; i < 4; ++i)
      af[i] = ldb8(&AsB[(wm * 64 + i * 16 + l15) * 32 + ((lq ^ swz2) * 8)]);
    #pragma unroll
    for (int j = 0; j < JT; ++j)
      bfr[j] = ldb8(&BsB[(wn * (BN / 2) + j * 16 + l15) * 32 + ((lq ^ swz2) * 8)]);
    #pragma unroll
    for (int i = 0; i < 4; ++i)
      #pragma unroll
      for (int j = 0; j < JT; ++j)
        acc[i][j] = __builtin_amdgcn_mfma_f32_16x16x32_bf16(af[i], bfr[j], acc[i][j], 0, 0, 0);
    cur = (cur == 2) ? 0 : cur + 1;
  }

  if (MODE == 1 && n0 >= 2048) {
    // V block: transposed + kv-permuted into Vt[(b*16+h)*64+d][blk64 + pos]
    #pragma unroll
    for (int i = 0; i < 4; ++i) {
      int rowb = m0 + wm * 64 + i * 16 + lq * 4;   // 4 consecutive t
      int b_ = rowb >> 11, t0 = rowb & 2047;
      int tl = t0 & 63;
      int c = tl >> 4, ll = (tl >> 2) & 3;
      int pos0 = (c >> 1) * 32 + ll * 8 + (c & 1) * 4;
      size_t tdst = (size_t)(t0 & ~63) + pos0;
      #pragma unroll
      for (int j = 0; j < JT; ++j) {
        int col = n0 + wn * (BN / 2) + j * 16 + l15;
        int hd = col - 2048;
        float bsv = bias[col];
        u16x4 pk;
        #pragma unroll
        for (int r = 0; r < 4; ++r) pk[r] = f2bf(acc[i][j][r] + bsv);
        *(u16x4*)&Vt[(size_t)(b_ * 1024 + hd) * Tt + tdst] = pk;
      }
    }
  } else {
    const int ldc = (MODE == 1) ? 2048 : N;
    #pragma unroll
    for (int i = 0; i < 4; ++i) {
      int row = m0 + wm * 64 + i * 16 + lq * 4;
      #pragma unroll
      for (int j = 0; j < JT; ++j) {
        int col = n0 + wn * (BN / 2) + j * 16 + l15;
        float bsv = bias[col];
        #pragma unroll
        for (int r = 0; r < 4; ++r) {
          float v = acc[i][j][r] + bsv;
          if (MODE == 1) ((u16*)Cout)[(size_t)(row + r) * ldc + col] = f2bf(v);
          else           ((float*)Cout)[(size_t)(row + r) * ldc + col] = v;
        }
      }
    }
  }
}

// ======== gemm_bt64: BK=64 variant for gemm2 (R8, kept) ========
__global__ __launch_bounds__(256, 3)
void gemm_bt64(const u16* __restrict__ A, const u16* __restrict__ Bt,
               const float* __restrict__ bias, float* __restrict__ Cout,
               int M, int N, int K) {
  __shared__ u16 As[2][128 * 64];
  __shared__ u16 Bs[2][64 * 64];
  const int tid = threadIdx.x;
  const int ln = tid & 63, w = tid >> 6;
  const int wm = w >> 1, wn = w & 1;
  const int l15 = ln & 15, lq = ln >> 4;
  const int swz = l15 & 7;
  const int m0 = blockIdx.y * 128, n0 = blockIdx.x * 64;

  int aoff[4], boff[2];
  #pragma unroll
  for (int i = 0; i < 4; ++i) {             // A: 128 rows x 8 chunks = 1024 slots
    int s = i * 256 + tid;
    aoff[i] = (m0 + (s >> 3)) * K + (((s & 7) ^ ((s >> 3) & 7)) * 8);
  }
  #pragma unroll
  for (int i = 0; i < 2; ++i) {             // B: 64 rows x 8 chunks = 512 slots
    int s = i * 256 + tid;
    boff[i] = (n0 + (s >> 3)) * K + (((s & 7) ^ ((s >> 3) & 7)) * 8);
  }

  f32x4 acc[4][2];
  #pragma unroll
  for (int i = 0; i < 4; ++i)
    #pragma unroll
    for (int j = 0; j < 2; ++j) acc[i][j] = (f32x4){0.f, 0.f, 0.f, 0.f};

  const int NK = K >> 6;   // 16

  auto STAGE = [&](int buf, int t) {
    const int k0 = t * 64;
    #pragma unroll
    for (int i = 0; i < 4; ++i)
      gl2lds16(A + aoff[i] + k0, (char*)As[buf] + (size_t)(i * 256 + w * 64) * 16);
    #pragma unroll
    for (int i = 0; i < 2; ++i)
      gl2lds16(Bt + boff[i] + k0, (char*)Bs[buf] + (size_t)(i * 256 + w * 64) * 16);
  };

  STAGE(0, 0);
  int cur = 0;
  for (int it = 0; it < NK; ++it) {
    __syncthreads();                  // tile `it` landed; buf cur^1 readers done
    if (it + 1 < NK) STAGE(cur ^ 1, it + 1);
    const u16* AsB = As[cur];
    const u16* BsB = Bs[cur];
    bf16x8 af[4][2], bfr[2][2];
    #pragma unroll
    for (int i = 0; i < 4; ++i)
      #pragma unroll
      for (int kk = 0; kk < 2; ++kk)
        af[i][kk] = ldb8(&AsB[(wm * 64 + i * 16 + l15) * 64 + (((kk * 4 + lq) ^ swz) * 8)]);
    #pragma unroll
    for (int j = 0; j < 2; ++j)
      #pragma unroll
      for (int kk = 0; kk < 2; ++kk)
        bfr[j][kk] = ldb8(&BsB[(wn * 32 + j * 16 + l15) * 64 + (((kk * 4 + lq) ^ swz) * 8)]);
    __builtin_amdgcn_s_setprio(1);
    #pragma unroll
    for (int i = 0; i < 4; ++i)
      #pragma unroll
      for (int j = 0; j < 2; ++j)
        #pragma unroll
        for (int kk = 0; kk < 2; ++kk)
          acc[i][j] = __builtin_amdgcn_mfma_f32_16x16x32_bf16(af[i][kk], bfr[j][kk], acc[i][j], 0, 0, 0);
    __builtin_amdgcn_s_setprio(0);
    cur ^= 1;
  }

  #pragma unroll
  for (int i = 0; i < 4; ++i) {
    int row = m0 + wm * 64 + i * 16 + lq * 4;
    #pragma unroll
    for (int j = 0; j < 2; ++j) {
      int col = n0 + wn * 32 + j * 16 + l15;
      float bsv = bias[col];
      #pragma unroll
      for (int r = 0; r < 4; ++r)
        Cout[(size_t)(row + r) * N + col] = acc[i][j][r] + bsv;
    }
  }
}

// ===== fused causal flash attention — KVBLK=128, K in LDS, V DIRECT from L2 =====
// Round-9 change (guide Common-mistake #7 / m169 precedent): V is L2-resident
// (K+V per bh = 512KB << 4MB; all 32 q-tile blocks of a bh land on the same
// XCD since bx%8 = bh%8) and pre-permuted by gemm1 so the PV A-fragment is a
// contiguous 16B at a LINEAR global chunk: the staged reader's XOR
// ((ks*4+lq)^l15) cancelled against the staging swizzle (^(d&15), d&15==l15),
// so direct global addr = vbase + d*Tt + kk + (ks*4+lq)*8 reads byte-identical
// data. Dropping V staging: LDS traffic/block-iter 160->80KB (LDS was ~45%
// busy, largest pipe), LDS 64->32KB -> __launch_bounds__(256,3) = 3 blocks/CU
// (+50% waves). V loads issue right after the barrier BEFORE K-staging (FIFO
// vmcnt: PV's wait on V regs leaves K-stage loads in flight); fragments for
// k-slots 2,3 ping-pong-reload mid-PV to keep VGPR under the 168 cap.
__device__ __forceinline__ bf16x8 packp(const f32x4& a, const f32x4& b) {
  bf16x8 r;
  #pragma unroll
  for (int i = 0; i < 4; ++i) { r[i] = (__bf16)a[i]; r[i + 4] = (__bf16)b[i]; }
  return r;
}
__device__ __forceinline__ bf16x8 qscale(const u16* p) {
  u16x8 q = *(const u16x8*)p;
  u16x8 s;
  #pragma unroll
  for (int j = 0; j < 8; ++j) s[j] = f2bf(bf2f(q[j]) * SCALE2);
  return __builtin_bit_cast(bf16x8, s);
}

__global__ __launch_bounds__(256, 3)
void attn_fused(const u16* __restrict__ qk, const u16* __restrict__ vt,
                u16* __restrict__ y) {
  __shared__ u16 Ks[2][128 * 64];   // swizzled [kv-row][d], double-buffered (32KB)
  const int tid = threadIdx.x;
  const int ln = tid & 63, w = tid >> 6;
  const int l15 = ln & 15, lq = ln >> 4;
  const int swzK = l15 & 7;
  const int bx = blockIdx.x;
  const int bh = bx & 31;
  const int h  = bh & 15, b = bh >> 4;
  const int rr_ = bx >> 8, g = (bx >> 5) & 7;
  const int qt = (rr_ == 0) ? 31 - g : (rr_ == 1) ? 16 + g : (rr_ == 2) ? 15 - g : g;
  const int q0w = qt * 64 + w * 16;

  const u16* qbase = qk + (size_t)(b * Tt) * 2048 + h * HD;
  const u16* kbase = qk + (size_t)(b * Tt) * 2048 + 1024 + h * HD;
  const u16* vbase = vt + (size_t)(b * 1024 + h * HD) * Tt;

  int koff[4];
  #pragma unroll
  for (int i = 0; i < 4; ++i) {
    int s = i * 256 + tid;
    koff[i] = (s >> 3) * 2048 + (((s & 7) ^ ((s >> 3) & 7)) * 8);
  }

  const u16* qrA = qbase + (size_t)(q0w + l15) * 2048;
  bf16x8 qA0 = qscale(qrA + lq * 8), qA1 = qscale(qrA + 32 + lq * 8);

  bf16x8 ones;
  #pragma unroll
  for (int j = 0; j < 8; ++j) ones[j] = (__bf16)1.0f;

  f32x4 o[4];
  #pragma unroll
  for (int j = 0; j < 4; ++j) o[j] = (f32x4){0, 0, 0, 0};
  f32x4 lacc = (f32x4){0, 0, 0, 0};
  float m = -__builtin_inff();
  const int qg = q0w + l15;
  const int nkv = (qt >> 1) + 1;

  auto KSTAGE = [&](int buf, int t) {
    const u16* ks = kbase + (size_t)(t * 128) * 2048;
    #pragma unroll
    for (int i = 0; i < 4; ++i)
      gl2lds16(ks + koff[i], (char*)Ks[buf] + (size_t)(i * 256 + w * 64) * 16);
  };

  KSTAGE(0, 0);
  int cur = 0;
  for (int it = 0; it < nkv; ++it) {
    const int kk = it * 128;
    __syncthreads();                 // K tile `it` landed; buf cur^1 readers done

    // V direct loads (tile it, k-slots 0 and 1) — issued before K-staging so
    // PV's vmcnt wait on these regs leaves the K-stage loads in flight.
    const u16* vrow = vbase + kk;
    bf16x8 vfA[4], vfB[4];
    #pragma unroll
    for (int jd = 0; jd < 4; ++jd) {
      const u16* vp = vrow + (size_t)(jd * 16 + l15) * Tt;
      vfA[jd] = ldb8(vp + (0 * 4 + lq) * 8);
      vfB[jd] = ldb8(vp + (1 * 4 + lq) * 8);
    }

    if (it + 1 < nkv) KSTAGE(cur ^ 1, it + 1);
    const u16* KsB = Ks[cur];

    // S^T = K * Q^T : 128 kv rows = 8 row-subtiles x 2 k-halves
    f32x4 t[8];
    #pragma unroll
    for (int i = 0; i < 8; ++i) t[i] = (f32x4){0, 0, 0, 0};
    __builtin_amdgcn_s_setprio(1);
    #pragma unroll
    for (int i = 0; i < 8; ++i) {
      bf16x8 kf0 = ldb8(&KsB[(i * 16 + l15) * 64 + ((lq      ^ swzK) * 8)]);
      bf16x8 kf1 = ldb8(&KsB[(i * 16 + l15) * 64 + (((lq + 4) ^ swzK) * 8)]);
      t[i] = __builtin_amdgcn_mfma_f32_16x16x32_bf16(kf0, qA0, t[i], 0, 0, 0);
      t[i] = __builtin_amdgcn_mfma_f32_16x16x32_bf16(kf1, qA1, t[i], 0, 0, 0);
    }
    __builtin_amdgcn_s_setprio(0);

    if (it == nkv - 1) {
      #pragma unroll
      for (int i = 0; i < 8; ++i)
        #pragma unroll
        for (int r = 0; r < 4; ++r) {
          int kv = kk + i * 16 + lq * 4 + r;
          if (kv > qg) t[i][r] = -__builtin_inff();
        }
    }

    float a0 = fmaxf(fmaxf(t[0][0], t[0][1]), fmaxf(t[0][2], t[0][3]));
    float a1 = fmaxf(fmaxf(t[1][0], t[1][1]), fmaxf(t[1][2], t[1][3]));
    float a2 = fmaxf(fmaxf(t[2][0], t[2][1]), fmaxf(t[2][2], t[2][3]));
    float a3 = fmaxf(fmaxf(t[3][0], t[3][1]), fmaxf(t[3][2], t[3][3]));
    float a4 = fmaxf(fmaxf(t[4][0], t[4][1]), fmaxf(t[4][2], t[4][3]));
    float a5 = fmaxf(fmaxf(t[5][0], t[5][1]), fmaxf(t[5][2], t[5][3]));
    float a6 = fmaxf(fmaxf(t[6][0], t[6][1]), fmaxf(t[6][2], t[6][3]));
    float a7 = fmaxf(fmaxf(t[7][0], t[7][1]), fmaxf(t[7][2], t[7][3]));
    float mx = fmaxf(fmaxf(fmaxf(a0, a1), fmaxf(a2, a3)),
                     fmaxf(fmaxf(a4, a5), fmaxf(a6, a7)));
    mx = fmaxf(mx, __shfl_xor(mx, 16));
#if __has_builtin(__builtin_amdgcn_permlane32_swap)
    {
      unsigned mu = __builtin_bit_cast(unsigned, mx);
      auto r2 = __builtin_amdgcn_permlane32_swap(mu, mu, false, false);
      mx = fmaxf(__builtin_bit_cast(float, (unsigned)r2[0]),
                 __builtin_bit_cast(float, (unsigned)r2[1]));
    }
#else
    mx = fmaxf(mx, __shfl_xor(mx, 32));
#endif

    if (!__all(mx <= m + 8.0f)) {
      float mn = fmaxf(m, mx);
      float al = __builtin_amdgcn_exp2f(m - mn);
      m = mn;
      lacc[0] *= al;
      #pragma unroll
      for (int jd = 0; jd < 4; ++jd)
        #pragma unroll
        for (int r = 0; r < 4; ++r) o[jd][r] *= al;
    }
    #pragma unroll
    for (int i = 0; i < 8; ++i)
      #pragma unroll
      for (int r = 0; r < 4; ++r)
        t[i][r] = __builtin_amdgcn_exp2f(t[i][r] - m);

    bf16x8 pk_[4];
    #pragma unroll
    for (int ks = 0; ks < 4; ++ks) pk_[ks] = packp(t[2 * ks], t[2 * ks + 1]);

    // PV: O^T += V^T * P, l += ones * P.  Ping-pong V regs: use A(ks0),
    // reload A<-ks2; use B(ks1), reload B<-ks3; use A(ks2); use B(ks3).
    __builtin_amdgcn_s_setprio(1);
    lacc = __builtin_amdgcn_mfma_f32_16x16x32_bf16(ones, pk_[0], lacc, 0, 0, 0);
    #pragma unroll
    for (int jd = 0; jd < 4; ++jd)
      o[jd] = __builtin_amdgcn_mfma_f32_16x16x32_bf16(vfA[jd], pk_[0], o[jd], 0, 0, 0);
    #pragma unroll
    for (int jd = 0; jd < 4; ++jd)
      vfA[jd] = ldb8(vrow + (size_t)(jd * 16 + l15) * Tt + (2 * 4 + lq) * 8);
    lacc = __builtin_amdgcn_mfma_f32_16x16x32_bf16(ones, pk_[1], lacc, 0, 0, 0);
    #pragma unroll
    for (int jd = 0; jd < 4; ++jd)
      o[jd] = __builtin_amdgcn_mfma_f32_16x16x32_bf16(vfB[jd], pk_[1], o[jd], 0, 0, 0);
    #pragma unroll
    for (int jd = 0; jd < 4; ++jd)
      vfB[jd] = ldb8(vrow + (size_t)(jd * 16 + l15) * Tt + (3 * 4 + lq) * 8);
    lacc = __builtin_amdgcn_mfma_f32_16x16x32_bf16(ones, pk_[2], lacc, 0, 0, 0);
    #pragma unroll
    for (int jd = 0; jd < 4; ++jd)
      o[jd] = __builtin_amdgcn_mfma_f32_16x16x32_bf16(vfA[jd], pk_[2], o[jd], 0, 0, 0);
    lacc = __builtin_amdgcn_mfma_f32_16x16x32_bf16(ones, pk_[3], lacc, 0, 0, 0);
    #pragma unroll
    for (int jd = 0; jd < 4; ++jd)
      o[jd] = __builtin_amdgcn_mfma_f32_16x16x32_bf16(vfB[jd], pk_[3], o[jd], 0, 0, 0);
    __builtin_amdgcn_s_setprio(0);
    cur ^= 1;
  }

  float inv = 1.f / lacc[0];
  const size_t ybase = (size_t)(b * Tt + q0w + l15) * Cc + h * HD;
  #pragma unroll
  for (int jd = 0; jd < 4; ++jd) {
    u16x4 pk;
    #pragma unroll
    for (int r = 0; r < 4; ++r) pk[r] = f2bf(o[jd][r] * inv);
    *(u16x4*)&y[ybase + jd * 16 + lq * 4] = pk;
  }
}

extern "C" void kernel_launch(void* const* d_in, const int* in_sizes, int n_in,
                              void* d_out, int out_size, void* d_ws, size_t ws_size,
                              hipStream_t stream) {
  const float* x      = (const float*)d_in[0];
  const float* w_attn = (const float*)d_in[1];
  const float* b_attn = (const float*)d_in[2];
  const float* w_proj = (const float*)d_in[3];
  const float* b_proj = (const float*)d_in[4];
  float* out = (float*)d_out;

  char* ws = (char*)d_ws;
  u16* xb  = (u16*)(ws + 0);          // 4096x1024 bf16   (8 MB)
  u16* wat = (u16*)(ws + 8388608);    // 3072x1024 bf16   (6 MB)   w_attn^T
  u16* wpt = (u16*)(ws + 14680064);   // 1024x1024 bf16   (2 MB)   w_proj^T
  u16* qkb = (u16*)(ws + 16777216);   // 4096x2048 bf16   (16 MB)  Q,K
  u16* vtb = (u16*)(ws + 33554432);   // 2048x2048 bf16   (8 MB)   V^T (permuted)
  u16* yb  = (u16*)(ws + 41943040);   // 4096x1024 bf16   (8 MB)

  prep_kernel<<<5120, 256, 0, stream>>>(x, w_attn, w_proj, xb, wat, wpt);
  gemm_bt<1, 128, 3><<<dim3(24, 32), 256, 0, stream>>>(xb, wat, b_attn, (void*)qkb, vtb, 4096, 3072, 1024);
  attn_fused<<<1024, 256, 0, stream>>>(qkb, vtb, yb);
  gemm_bt64<<<dim3(16, 32), 256, 0, stream>>>(yb, wpt, b_proj, out, 4096, 1024, 1024);
}

// Round 10
// 168.613 us; speedup vs baseline: 1.2227x; 1.2227x over previous
//
#include <hip/hip_runtime.h>
#include <stdint.h>

#define Bb 2
#define Tt 2048
#define Cc 1024
#define Hh 16
#define HD 64
#define C3 3072

typedef __bf16 bf16x8 __attribute__((ext_vector_type(8)));
typedef float  f32x4  __attribute__((ext_vector_type(4)));
typedef unsigned short u16;
typedef u16 u16x8 __attribute__((ext_vector_type(8)));
typedef u16 u16x4 __attribute__((ext_vector_type(4)));

#define SCALE2 0.18033688f  /* 1/sqrt(64) * log2(e) */

__device__ __forceinline__ u16 f2bf(float f) {
  union { float f; unsigned u; } v; v.f = f;
  return (u16)((v.u + 0x7fffu + ((v.u >> 16) & 1u)) >> 16);  // RNE
}
__device__ __forceinline__ float bf2f(u16 a) {
  union { unsigned u; float f; } v; v.u = ((unsigned)a) << 16; return v.f;
}

// async global->LDS, 16B per lane. LDS dest = wave-uniform base + lane*16.
__device__ __forceinline__ void gl2lds16(const void* g, void* s) {
  __builtin_amdgcn_global_load_lds(
      (__attribute__((address_space(1))) void*)(g),
      (__attribute__((address_space(3))) void*)(s), 16, 0, 0);
}

__device__ __forceinline__ bf16x8 ldb8(const u16* p) {
  return __builtin_bit_cast(bf16x8, *(const u16x8*)p);
}

// counted vmcnt wait: allow N of this wave's VMEM ops to stay in flight.
template <int N>
__device__ __forceinline__ void vmwait() {
  asm volatile("s_waitcnt vmcnt(%0)" :: "n"(N) : "memory");
}
// raw s_barrier (no compiler vmcnt(0) drain); sched_barrier pins motion.
__device__ __forceinline__ void barrier_nodrain() {
  __builtin_amdgcn_s_barrier();
  __builtin_amdgcn_sched_barrier(0);
}

// T1: XCD-aware block remap. HW dispatches linear block ids round-robin over
// 8 XCDs; remap so each XCD owns a CONTIGUOUS chunk of the logical tile order
// (neighboring tiles share A-panels -> their reuse becomes L2-local).
// Requires nwg % 8 == 0 (bijective). gemm1: 768 ok, gemm2: 512 ok.
__device__ __forceinline__ int xcd_swizzle(int lin, int nwg) {
  const int q = nwg >> 3;
  return (lin & 7) * q + (lin >> 3);
}

// ---------------- merged prep: cvt_x + w_attn^T + w_proj^T ----------------
__global__ __launch_bounds__(256)
void prep_kernel(const float* __restrict__ x, const float* __restrict__ w_attn,
                 const float* __restrict__ w_proj, u16* __restrict__ xb,
                 u16* __restrict__ wat, u16* __restrict__ wpt) {
  __shared__ u16 tile[64][65];
  const int blk = blockIdx.x;
  const int tid = threadIdx.x;
  if (blk < 4096) {
    int i = blk * 256 + tid;
    float4 v = ((const float4*)x)[i];
    u16x4 o = { f2bf(v.x), f2bf(v.y), f2bf(v.z), f2bf(v.w) };
    ((u16x4*)xb)[i] = o;
    return;
  }
  const float* in; u16* out; int R, C, c0, r0;
  if (blk < 4096 + 768) {
    int t = blk - 4096;
    in = w_attn; out = wat; R = 1024; C = 3072;
    c0 = (t % 48) * 64; r0 = (t / 48) * 64;
  } else {
    int t = blk - 4864;
    in = w_proj; out = wpt; R = 1024; C = 1024;
    c0 = (t & 15) * 64; r0 = (t >> 4) * 64;
  }
  int xx = tid & 63, yy = tid >> 6;
  #pragma unroll
  for (int rr = yy; rr < 64; rr += 4)
    tile[rr][xx] = f2bf(in[(size_t)(r0 + rr) * C + c0 + xx]);
  __syncthreads();
  #pragma unroll
  for (int rr = yy; rr < 64; rr += 4)
    out[(size_t)(c0 + rr) * R + r0 + xx] = tile[xx][rr];
}

// ---------------- bf16 GEMM: C[M][N] = A[M][K] * Bt[N][K]^T + bias ----------------
// R5 structure (best measured gemm1 ~35us): 128xBN tile, BK=32, triple-buffered
// LDS, depth-2 prefetch, counted-vmcnt barriers. Round-10: + T1 XCD swizzle of
// the block id (grid dim3(N/BN, M/128), x-fastest linearization).
// MODE 1 (BN=128): bf16 out ldc=2048 for Q,K; V cols (>=2048) transposed +
// kv-permuted into Vt.
template <int MODE, int BN, int MINW>
__global__ __launch_bounds__(256, MINW)
void gemm_bt(const u16* __restrict__ A, const u16* __restrict__ Bt,
             const float* __restrict__ bias, void* __restrict__ Cout,
             u16* __restrict__ Vt, int M, int N, int K) {
  __shared__ u16 As[3][128 * 32];
  __shared__ u16 Bs[3][BN * 32];
  constexpr int JT = BN / 32;
  constexpr int NB = BN / 128 + 1;
  constexpr int L  = 2 + NB;
  const int tid = threadIdx.x;
  const int ln  = tid & 63;
  const int w   = tid >> 6;
  const int wm  = w >> 1, wn = w & 1;
  const int l15 = ln & 15, lq = ln >> 4;
  const int swz2 = (l15 >> 1) & 3;
  // T1 swizzle: each XCD gets a contiguous run of logical tiles
  const int nbx = gridDim.x;
  const int wg  = xcd_swizzle(blockIdx.y * nbx + blockIdx.x, nbx * gridDim.y);
  const int m0 = (wg / nbx) * 128, n0 = (wg % nbx) * BN;

  int aoff[2], boff[NB];
  #pragma unroll
  for (int i = 0; i < 2; ++i) {
    int s = i * 256 + tid;
    int row = s >> 2, cg = (s & 3) ^ ((s >> 3) & 3);
    aoff[i] = (m0 + row) * K + cg * 8;
  }
  #pragma unroll
  for (int i = 0; i < NB; ++i) {
    int s = i * 256 + tid;
    int row = s >> 2, cg = (s & 3) ^ ((s >> 3) & 3);
    boff[i] = (n0 + row) * K + cg * 8;
  }

  f32x4 acc[4][JT];
  #pragma unroll
  for (int i = 0; i < 4; ++i)
    #pragma unroll
    for (int j = 0; j < JT; ++j)
      acc[i][j] = (f32x4){0.f, 0.f, 0.f, 0.f};

  const int NK = K >> 5;

  auto STAGE = [&](int buf, int t) {
    const int k0 = t * 32;
    #pragma unroll
    for (int i = 0; i < 2; ++i)
      gl2lds16(A + aoff[i] + k0, (char*)As[buf] + (size_t)(i * 256 + w * 64) * 16);
    #pragma unroll
    for (int i = 0; i < NB; ++i)
      gl2lds16(Bt + boff[i] + k0, (char*)Bs[buf] + (size_t)(i * 256 + w * 64) * 16);
  };

  STAGE(0, 0);
  if (NK > 1) STAGE(1, 1);

  int cur = 0;
  for (int it = 0; it < NK; ++it) {
    if (it + 1 < NK) vmwait<L>(); else vmwait<0>();
    barrier_nodrain();
    if (it + 2 < NK) STAGE(cur == 0 ? 2 : cur - 1, it + 2);
    const u16* AsB = As[cur];
    const u16* BsB = Bs[cur];
    bf16x8 af[4], bfr[JT];
    #pragma unroll
    for (int i = 0; i < 4; ++i)
      af[i] = ldb8(&AsB[(wm * 64 + i * 16 + l15) * 32 + ((lq ^ swz2) * 8)]);
    #pragma unroll
    for (int j = 0; j < JT; ++j)
      bfr[j] = ldb8(&BsB[(wn * (BN / 2) + j * 16 + l15) * 32 + ((lq ^ swz2) * 8)]);
    #pragma unroll
    for (int i = 0; i < 4; ++i)
      #pragma unroll
      for (int j = 0; j < JT; ++j)
        acc[i][j] = __builtin_amdgcn_mfma_f32_16x16x32_bf16(af[i], bfr[j], acc[i][j], 0, 0, 0);
    cur = (cur == 2) ? 0 : cur + 1;
  }

  if (MODE == 1 && n0 >= 2048) {
    // V block: transposed + kv-permuted into Vt[(b*16+h)*64+d][blk64 + pos]
    #pragma unroll
    for (int i = 0; i < 4; ++i) {
      int rowb = m0 + wm * 64 + i * 16 + lq * 4;   // 4 consecutive t
      int b_ = rowb >> 11, t0 = rowb & 2047;
      int tl = t0 & 63;
      int c = tl >> 4, ll = (tl >> 2) & 3;
      int pos0 = (c >> 1) * 32 + ll * 8 + (c & 1) * 4;
      size_t tdst = (size_t)(t0 & ~63) + pos0;
      #pragma unroll
      for (int j = 0; j < JT; ++j) {
        int col = n0 + wn * (BN / 2) + j * 16 + l15;
        int hd = col - 2048;
        float bsv = bias[col];
        u16x4 pk;
        #pragma unroll
        for (int r = 0; r < 4; ++r) pk[r] = f2bf(acc[i][j][r] + bsv);
        *(u16x4*)&Vt[(size_t)(b_ * 1024 + hd) * Tt + tdst] = pk;
      }
    }
  } else {
    const int ldc = (MODE == 1) ? 2048 : N;
    #pragma unroll
    for (int i = 0; i < 4; ++i) {
      int row = m0 + wm * 64 + i * 16 + lq * 4;
      #pragma unroll
      for (int j = 0; j < JT; ++j) {
        int col = n0 + wn * (BN / 2) + j * 16 + l15;
        float bsv = bias[col];
        #pragma unroll
        for (int r = 0; r < 4; ++r) {
          float v = acc[i][j][r] + bsv;
          if (MODE == 1) ((u16*)Cout)[(size_t)(row + r) * ldc + col] = f2bf(v);
          else           ((float*)Cout)[(size_t)(row + r) * ldc + col] = v;
        }
      }
    }
  }
}

// ======== gemm_bt64: BK=64 variant for gemm2 (R8) + T1 XCD swizzle ========
__global__ __launch_bounds__(256, 3)
void gemm_bt64(const u16* __restrict__ A, const u16* __restrict__ Bt,
               const float* __restrict__ bias, float* __restrict__ Cout,
               int M, int N, int K) {
  __shared__ u16 As[2][128 * 64];
  __shared__ u16 Bs[2][64 * 64];
  const int tid = threadIdx.x;
  const int ln = tid & 63, w = tid >> 6;
  const int wm = w >> 1, wn = w & 1;
  const int l15 = ln & 15, lq = ln >> 4;
  const int swz = l15 & 7;
  const int nbx = gridDim.x;
  const int wg  = xcd_swizzle(blockIdx.y * nbx + blockIdx.x, nbx * gridDim.y);
  const int m0 = (wg / nbx) * 128, n0 = (wg % nbx) * 64;

  int aoff[4], boff[2];
  #pragma unroll
  for (int i = 0; i < 4; ++i) {             // A: 128 rows x 8 chunks = 1024 slots
    int s = i * 256 + tid;
    aoff[i] = (m0 + (s >> 3)) * K + (((s & 7) ^ ((s >> 3) & 7)) * 8);
  }
  #pragma unroll
  for (int i = 0; i < 2; ++i) {             // B: 64 rows x 8 chunks = 512 slots
    int s = i * 256 + tid;
    boff[i] = (n0 + (s >> 3)) * K + (((s & 7) ^ ((s >> 3) & 7)) * 8);
  }

  f32x4 acc[4][2];
  #pragma unroll
  for (int i = 0; i < 4; ++i)
    #pragma unroll
    for (int j = 0; j < 2; ++j) acc[i][j] = (f32x4){0.f, 0.f, 0.f, 0.f};

  const int NK = K >> 6;   // 16

  auto STAGE = [&](int buf, int t) {
    const int k0 = t * 64;
    #pragma unroll
    for (int i = 0; i < 4; ++i)
      gl2lds16(A + aoff[i] + k0, (char*)As[buf] + (size_t)(i * 256 + w * 64) * 16);
    #pragma unroll
    for (int i = 0; i < 2; ++i)
      gl2lds16(Bt + boff[i] + k0, (char*)Bs[buf] + (size_t)(i * 256 + w * 64) * 16);
  };

  STAGE(0, 0);
  int cur = 0;
  for (int it = 0; it < NK; ++it) {
    __syncthreads();                  // tile `it` landed; buf cur^1 readers done
    if (it + 1 < NK) STAGE(cur ^ 1, it + 1);
    const u16* AsB = As[cur];
    const u16* BsB = Bs[cur];
    bf16x8 af[4][2], bfr[2][2];
    #pragma unroll
    for (int i = 0; i < 4; ++i)
      #pragma unroll
      for (int kk = 0; kk < 2; ++kk)
        af[i][kk] = ldb8(&AsB[(wm * 64 + i * 16 + l15) * 64 + (((kk * 4 + lq) ^ swz) * 8)]);
    #pragma unroll
    for (int j = 0; j < 2; ++j)
      #pragma unroll
      for (int kk = 0; kk < 2; ++kk)
        bfr[j][kk] = ldb8(&BsB[(wn * 32 + j * 16 + l15) * 64 + (((kk * 4 + lq) ^ swz) * 8)]);
    __builtin_amdgcn_s_setprio(1);
    #pragma unroll
    for (int i = 0; i < 4; ++i)
      #pragma unroll
      for (int j = 0; j < 2; ++j)
        #pragma unroll
        for (int kk = 0; kk < 2; ++kk)
          acc[i][j] = __builtin_amdgcn_mfma_f32_16x16x32_bf16(af[i][kk], bfr[j][kk], acc[i][j], 0, 0, 0);
    __builtin_amdgcn_s_setprio(0);
    cur ^= 1;
  }

  #pragma unroll
  for (int i = 0; i < 4; ++i) {
    int row = m0 + wm * 64 + i * 16 + lq * 4;
    #pragma unroll
    for (int j = 0; j < 2; ++j) {
      int col = n0 + wn * 32 + j * 16 + l15;
      float bsv = bias[col];
      #pragma unroll
      for (int r = 0; r < 4; ++r)
        Cout[(size_t)(row + r) * N + col] = acc[i][j][r] + bsv;
    }
  }
}

// ============ fused causal flash attention — KVBLK=128, O^T (R5/R8 best) ============
// REVERTED from round 9: V staging restored. R9's direct-from-global V loads
// scattered 16B/lane at 4KB stride (16 cache lines per wave-instruction) and
// doubled attn's time -- the LDS staging pass IS the coalescer for V^T.
__device__ __forceinline__ bf16x8 packp(const f32x4& a, const f32x4& b) {
  bf16x8 r;
  #pragma unroll
  for (int i = 0; i < 4; ++i) { r[i] = (__bf16)a[i]; r[i + 4] = (__bf16)b[i]; }
  return r;
}
__device__ __forceinline__ bf16x8 qscale(const u16* p) {
  u16x8 q = *(const u16x8*)p;
  u16x8 s;
  #pragma unroll
  for (int j = 0; j < 8; ++j) s[j] = f2bf(bf2f(q[j]) * SCALE2);
  return __builtin_bit_cast(bf16x8, s);
}

__global__ __launch_bounds__(256, 2)
void attn_fused(const u16* __restrict__ qk, const u16* __restrict__ vt,
                u16* __restrict__ y) {
  __shared__ u16 Ks[2][128 * 64];   // swizzled [kv-row][d], double-buffered
  __shared__ u16 Vts[2][64 * 128];  // swizzled [d-row][kv-permuted]
  const int tid = threadIdx.x;
  const int ln = tid & 63, w = tid >> 6;
  const int l15 = ln & 15, lq = ln >> 4;
  const int swzK = l15 & 7;
  const int bx = blockIdx.x;
  const int bh = bx & 31;
  const int h  = bh & 15, b = bh >> 4;
  const int rr_ = bx >> 8, g = (bx >> 5) & 7;
  const int qt = (rr_ == 0) ? 31 - g : (rr_ == 1) ? 16 + g : (rr_ == 2) ? 15 - g : g;
  const int q0w = qt * 64 + w * 16;

  const u16* qbase = qk + (size_t)(b * Tt) * 2048 + h * HD;
  const u16* kbase = qk + (size_t)(b * Tt) * 2048 + 1024 + h * HD;
  const u16* vbase = vt + (size_t)(b * 1024 + h * HD) * Tt;

  int koff[4], voff[4];
  #pragma unroll
  for (int i = 0; i < 4; ++i) {
    int s = i * 256 + tid;
    koff[i] = (s >> 3) * 2048 + (((s & 7) ^ ((s >> 3) & 7)) * 8);
    voff[i] = (s >> 4) * Tt + (((s & 15) ^ ((s >> 4) & 15)) * 8);
  }

  const u16* qrA = qbase + (size_t)(q0w + l15) * 2048;
  bf16x8 qA0 = qscale(qrA + lq * 8), qA1 = qscale(qrA + 32 + lq * 8);

  bf16x8 ones;
  #pragma unroll
  for (int j = 0; j < 8; ++j) ones[j] = (__bf16)1.0f;

  f32x4 o[4];
  #pragma unroll
  for (int j = 0; j < 4; ++j) o[j] = (f32x4){0, 0, 0, 0};
  f32x4 lacc = (f32x4){0, 0, 0, 0};
  float m = -__builtin_inff();
  const int qg = q0w + l15;
  const int nkv = (qt >> 1) + 1;

  auto STAGE = [&](int buf, int t) {
    const u16* ks = kbase + (size_t)(t * 128) * 2048;
    const u16* vs = vbase + t * 128;
    #pragma unroll
    for (int i = 0; i < 4; ++i) {
      gl2lds16(ks + koff[i], (char*)Ks[buf] + (size_t)(i * 256 + w * 64) * 16);
      gl2lds16(vs + voff[i], (char*)Vts[buf] + (size_t)(i * 256 + w * 64) * 16);
    }
  };

  STAGE(0, 0);
  int cur = 0;
  for (int it = 0; it < nkv; ++it) {
    const int kk = it * 128;
    __syncthreads();
    if (it + 1 < nkv) STAGE(cur ^ 1, it + 1);
    const u16* KsB  = Ks[cur];
    const u16* VtsB = Vts[cur];

    f32x4 t[8];
    #pragma unroll
    for (int i = 0; i < 8; ++i) t[i] = (f32x4){0, 0, 0, 0};
    __builtin_amdgcn_s_setprio(1);
    #pragma unroll
    for (int i = 0; i < 8; ++i) {
      bf16x8 kf0 = ldb8(&KsB[(i * 16 + l15) * 64 + ((lq      ^ swzK) * 8)]);
      bf16x8 kf1 = ldb8(&KsB[(i * 16 + l15) * 64 + (((lq + 4) ^ swzK) * 8)]);
      t[i] = __builtin_amdgcn_mfma_f32_16x16x32_bf16(kf0, qA0, t[i], 0, 0, 0);
      t[i] = __builtin_amdgcn_mfma_f32_16x16x32_bf16(kf1, qA1, t[i], 0, 0, 0);
    }
    __builtin_amdgcn_s_setprio(0);

    if (it == nkv - 1) {
      #pragma unroll
      for (int i = 0; i < 8; ++i)
        #pragma unroll
        for (int r = 0; r < 4; ++r) {
          int kv = kk + i * 16 + lq * 4 + r;
          if (kv > qg) t[i][r] = -__builtin_inff();
        }
    }

    float a0 = fmaxf(fmaxf(t[0][0], t[0][1]), fmaxf(t[0][2], t[0][3]));
    float a1 = fmaxf(fmaxf(t[1][0], t[1][1]), fmaxf(t[1][2], t[1][3]));
    float a2 = fmaxf(fmaxf(t[2][0], t[2][1]), fmaxf(t[2][2], t[2][3]));
    float a3 = fmaxf(fmaxf(t[3][0], t[3][1]), fmaxf(t[3][2], t[3][3]));
    float a4 = fmaxf(fmaxf(t[4][0], t[4][1]), fmaxf(t[4][2], t[4][3]));
    float a5 = fmaxf(fmaxf(t[5][0], t[5][1]), fmaxf(t[5][2], t[5][3]));
    float a6 = fmaxf(fmaxf(t[6][0], t[6][1]), fmaxf(t[6][2], t[6][3]));
    float a7 = fmaxf(fmaxf(t[7][0], t[7][1]), fmaxf(t[7][2], t[7][3]));
    float mx = fmaxf(fmaxf(fmaxf(a0, a1), fmaxf(a2, a3)),
                     fmaxf(fmaxf(a4, a5), fmaxf(a6, a7)));
    mx = fmaxf(mx, __shfl_xor(mx, 16));
#if __has_builtin(__builtin_amdgcn_permlane32_swap)
    {
      unsigned mu = __builtin_bit_cast(unsigned, mx);
      auto r2 = __builtin_amdgcn_permlane32_swap(mu, mu, false, false);
      mx = fmaxf(__builtin_bit_cast(float, (unsigned)r2[0]),
                 __builtin_bit_cast(float, (unsigned)r2[1]));
    }
#else
    mx = fmaxf(mx, __shfl_xor(mx, 32));
#endif

    if (!__all(mx <= m + 8.0f)) {
      float mn = fmaxf(m, mx);
      float al = __builtin_amdgcn_exp2f(m - mn);
      m = mn;
      lacc[0] *= al;
      #pragma unroll
      for (int jd = 0; jd < 4; ++jd)
        #pragma unroll
        for (int r = 0; r < 4; ++r) o[jd][r] *= al;
    }
    #pragma unroll
    for (int i = 0; i < 8; ++i)
      #pragma unroll
      for (int r = 0; r < 4; ++r)
        t[i][r] = __builtin_amdgcn_exp2f(t[i][r] - m);

    bf16x8 pk_[4];
    #pragma unroll
    for (int ks = 0; ks < 4; ++ks) pk_[ks] = packp(t[2 * ks], t[2 * ks + 1]);

    __builtin_amdgcn_s_setprio(1);
    #pragma unroll
    for (int ks = 0; ks < 4; ++ks) {
      lacc = __builtin_amdgcn_mfma_f32_16x16x32_bf16(ones, pk_[ks], lacc, 0, 0, 0);
      #pragma unroll
      for (int jd = 0; jd < 4; ++jd) {
        int d = jd * 16 + l15;
        bf16x8 vf = ldb8(&VtsB[d * 128 + (((ks * 4 + lq) ^ l15) * 8)]);
        o[jd] = __builtin_amdgcn_mfma_f32_16x16x32_bf16(vf, pk_[ks], o[jd], 0, 0, 0);
      }
    }
    __builtin_amdgcn_s_setprio(0);
    cur ^= 1;
  }

  float inv = 1.f / lacc[0];
  const size_t ybase = (size_t)(b * Tt + q0w + l15) * Cc + h * HD;
  #pragma unroll
  for (int jd = 0; jd < 4; ++jd) {
    u16x4 pk;
    #pragma unroll
    for (int r = 0; r < 4; ++r) pk[r] = f2bf(o[jd][r] * inv);
    *(u16x4*)&y[ybase + jd * 16 + lq * 4] = pk;
  }
}

extern "C" void kernel_launch(void* const* d_in, const int* in_sizes, int n_in,
                              void* d_out, int out_size, void* d_ws, size_t ws_size,
                              hipStream_t stream) {
  const float* x      = (const float*)d_in[0];
  const float* w_attn = (const float*)d_in[1];
  const float* b_attn = (const float*)d_in[2];
  const float* w_proj = (const float*)d_in[3];
  const float* b_proj = (const float*)d_in[4];
  float* out = (float*)d_out;

  char* ws = (char*)d_ws;
  u16* xb  = (u16*)(ws + 0);          // 4096x1024 bf16   (8 MB)
  u16* wat = (u16*)(ws + 8388608);    // 3072x1024 bf16   (6 MB)   w_attn^T
  u16* wpt = (u16*)(ws + 14680064);   // 1024x1024 bf16   (2 MB)   w_proj^T
  u16* qkb = (u16*)(ws + 16777216);   // 4096x2048 bf16   (16 MB)  Q,K
  u16* vtb = (u16*)(ws + 33554432);   // 2048x2048 bf16   (8 MB)   V^T (permuted)
  u16* yb  = (u16*)(ws + 41943040);   // 4096x1024 bf16   (8 MB)

  prep_kernel<<<5120, 256, 0, stream>>>(x, w_attn, w_proj, xb, wat, wpt);
  gemm_bt<1, 128, 3><<<dim3(24, 32), 256, 0, stream>>>(xb, wat, b_attn, (void*)qkb, vtb, 4096, 3072, 1024);
  attn_fused<<<1024, 256, 0, stream>>>(qkb, vtb, yb);
  gemm_bt64<<<dim3(16, 32), 256, 0, stream>>>(yb, wpt, b_proj, out, 4096, 1024, 1024);
}

// Round 11
// 167.760 us; speedup vs baseline: 1.2290x; 1.0051x over previous
//
#include <hip/hip_runtime.h>
#include <stdint.h>

#define Bb 2
#define Tt 2048
#define Cc 1024
#define Hh 16
#define HD 64
#define C3 3072

typedef __bf16 bf16x8 __attribute__((ext_vector_type(8)));
typedef float  f32x4  __attribute__((ext_vector_type(4)));
typedef unsigned short u16;
typedef u16 u16x8 __attribute__((ext_vector_type(8)));
typedef u16 u16x4 __attribute__((ext_vector_type(4)));

#define SCALE2 0.18033688f  /* 1/sqrt(64) * log2(e) */

__device__ __forceinline__ u16 f2bf(float f) {
  union { float f; unsigned u; } v; v.f = f;
  return (u16)((v.u + 0x7fffu + ((v.u >> 16) & 1u)) >> 16);  // RNE
}
__device__ __forceinline__ float bf2f(u16 a) {
  union { unsigned u; float f; } v; v.u = ((unsigned)a) << 16; return v.f;
}

// async global->LDS, 16B per lane. LDS dest = wave-uniform base + lane*16.
__device__ __forceinline__ void gl2lds16(const void* g, void* s) {
  __builtin_amdgcn_global_load_lds(
      (__attribute__((address_space(1))) void*)(g),
      (__attribute__((address_space(3))) void*)(s), 16, 0, 0);
}

__device__ __forceinline__ bf16x8 ldb8(const u16* p) {
  return __builtin_bit_cast(bf16x8, *(const u16x8*)p);
}

// counted vmcnt wait: allow N of this wave's VMEM ops to stay in flight.
template <int N>
__device__ __forceinline__ void vmwait() {
  asm volatile("s_waitcnt vmcnt(%0)" :: "n"(N) : "memory");
}
// raw s_barrier (no compiler vmcnt(0) drain); sched_barrier pins motion.
__device__ __forceinline__ void barrier_nodrain() {
  __builtin_amdgcn_s_barrier();
  __builtin_amdgcn_sched_barrier(0);
}

// T1: XCD-aware block remap. HW dispatches linear block ids round-robin over
// 8 XCDs; remap so each XCD owns a CONTIGUOUS chunk of the logical tile order
// (neighboring tiles share A-panels -> their reuse becomes L2-local).
// Requires nwg % 8 == 0 (bijective). gemm1: 768 ok, gemm2: 512 ok.
__device__ __forceinline__ int xcd_swizzle(int lin, int nwg) {
  const int q = nwg >> 3;
  return (lin & 7) * q + (lin >> 3);
}

// ---------------- merged prep: cvt_x + w_attn^T + w_proj^T ----------------
__global__ __launch_bounds__(256)
void prep_kernel(const float* __restrict__ x, const float* __restrict__ w_attn,
                 const float* __restrict__ w_proj, u16* __restrict__ xb,
                 u16* __restrict__ wat, u16* __restrict__ wpt) {
  __shared__ u16 tile[64][65];
  const int blk = blockIdx.x;
  const int tid = threadIdx.x;
  if (blk < 4096) {
    int i = blk * 256 + tid;
    float4 v = ((const float4*)x)[i];
    u16x4 o = { f2bf(v.x), f2bf(v.y), f2bf(v.z), f2bf(v.w) };
    ((u16x4*)xb)[i] = o;
    return;
  }
  const float* in; u16* out; int R, C, c0, r0;
  if (blk < 4096 + 768) {
    int t = blk - 4096;
    in = w_attn; out = wat; R = 1024; C = 3072;
    c0 = (t % 48) * 64; r0 = (t / 48) * 64;
  } else {
    int t = blk - 4864;
    in = w_proj; out = wpt; R = 1024; C = 1024;
    c0 = (t & 15) * 64; r0 = (t >> 4) * 64;
  }
  int xx = tid & 63, yy = tid >> 6;
  #pragma unroll
  for (int rr = yy; rr < 64; rr += 4)
    tile[rr][xx] = f2bf(in[(size_t)(r0 + rr) * C + c0 + xx]);
  __syncthreads();
  #pragma unroll
  for (int rr = yy; rr < 64; rr += 4)
    out[(size_t)(c0 + rr) * R + r0 + xx] = tile[xx][rr];
}

// ---------------- bf16 GEMM: C[M][N] = A[M][K] * Bt[N][K]^T + bias ----------------
// R5 structure + T1 XCD swizzle (R10 best). 128xBN tile, BK=32, triple-buffered
// LDS, depth-2 prefetch, counted-vmcnt barriers.
template <int MODE, int BN, int MINW>
__global__ __launch_bounds__(256, MINW)
void gemm_bt(const u16* __restrict__ A, const u16* __restrict__ Bt,
             const float* __restrict__ bias, void* __restrict__ Cout,
             u16* __restrict__ Vt, int M, int N, int K) {
  __shared__ u16 As[3][128 * 32];
  __shared__ u16 Bs[3][BN * 32];
  constexpr int JT = BN / 32;
  constexpr int NB = BN / 128 + 1;
  constexpr int L  = 2 + NB;
  const int tid = threadIdx.x;
  const int ln  = tid & 63;
  const int w   = tid >> 6;
  const int wm  = w >> 1, wn = w & 1;
  const int l15 = ln & 15, lq = ln >> 4;
  const int swz2 = (l15 >> 1) & 3;
  const int nbx = gridDim.x;
  const int wg  = xcd_swizzle(blockIdx.y * nbx + blockIdx.x, nbx * gridDim.y);
  const int m0 = (wg / nbx) * 128, n0 = (wg % nbx) * BN;

  int aoff[2], boff[NB];
  #pragma unroll
  for (int i = 0; i < 2; ++i) {
    int s = i * 256 + tid;
    int row = s >> 2, cg = (s & 3) ^ ((s >> 3) & 3);
    aoff[i] = (m0 + row) * K + cg * 8;
  }
  #pragma unroll
  for (int i = 0; i < NB; ++i) {
    int s = i * 256 + tid;
    int row = s >> 2, cg = (s & 3) ^ ((s >> 3) & 3);
    boff[i] = (n0 + row) * K + cg * 8;
  }

  f32x4 acc[4][JT];
  #pragma unroll
  for (int i = 0; i < 4; ++i)
    #pragma unroll
    for (int j = 0; j < JT; ++j)
      acc[i][j] = (f32x4){0.f, 0.f, 0.f, 0.f};

  const int NK = K >> 5;

  auto STAGE = [&](int buf, int t) {
    const int k0 = t * 32;
    #pragma unroll
    for (int i = 0; i < 2; ++i)
      gl2lds16(A + aoff[i] + k0, (char*)As[buf] + (size_t)(i * 256 + w * 64) * 16);
    #pragma unroll
    for (int i = 0; i < NB; ++i)
      gl2lds16(Bt + boff[i] + k0, (char*)Bs[buf] + (size_t)(i * 256 + w * 64) * 16);
  };

  STAGE(0, 0);
  if (NK > 1) STAGE(1, 1);

  int cur = 0;
  for (int it = 0; it < NK; ++it) {
    if (it + 1 < NK) vmwait<L>(); else vmwait<0>();
    barrier_nodrain();
    if (it + 2 < NK) STAGE(cur == 0 ? 2 : cur - 1, it + 2);
    const u16* AsB = As[cur];
    const u16* BsB = Bs[cur];
    bf16x8 af[4], bfr[JT];
    #pragma unroll
    for (int i = 0; i < 4; ++i)
      af[i] = ldb8(&AsB[(wm * 64 + i * 16 + l15) * 32 + ((lq ^ swz2) * 8)]);
    #pragma unroll
    for (int j = 0; j < JT; ++j)
      bfr[j] = ldb8(&BsB[(wn * (BN / 2) + j * 16 + l15) * 32 + ((lq ^ swz2) * 8)]);
    #pragma unroll
    for (int i = 0; i < 4; ++i)
      #pragma unroll
      for (int j = 0; j < JT; ++j)
        acc[i][j] = __builtin_amdgcn_mfma_f32_16x16x32_bf16(af[i], bfr[j], acc[i][j], 0, 0, 0);
    cur = (cur == 2) ? 0 : cur + 1;
  }

  if (MODE == 1 && n0 >= 2048) {
    // V block: transposed + kv-permuted into Vt[(b*16+h)*64+d][blk64 + pos]
    #pragma unroll
    for (int i = 0; i < 4; ++i) {
      int rowb = m0 + wm * 64 + i * 16 + lq * 4;   // 4 consecutive t
      int b_ = rowb >> 11, t0 = rowb & 2047;
      int tl = t0 & 63;
      int c = tl >> 4, ll = (tl >> 2) & 3;
      int pos0 = (c >> 1) * 32 + ll * 8 + (c & 1) * 4;
      size_t tdst = (size_t)(t0 & ~63) + pos0;
      #pragma unroll
      for (int j = 0; j < JT; ++j) {
        int col = n0 + wn * (BN / 2) + j * 16 + l15;
        int hd = col - 2048;
        float bsv = bias[col];
        u16x4 pk;
        #pragma unroll
        for (int r = 0; r < 4; ++r) pk[r] = f2bf(acc[i][j][r] + bsv);
        *(u16x4*)&Vt[(size_t)(b_ * 1024 + hd) * Tt + tdst] = pk;
      }
    }
  } else {
    const int ldc = (MODE == 1) ? 2048 : N;
    #pragma unroll
    for (int i = 0; i < 4; ++i) {
      int row = m0 + wm * 64 + i * 16 + lq * 4;
      #pragma unroll
      for (int j = 0; j < JT; ++j) {
        int col = n0 + wn * (BN / 2) + j * 16 + l15;
        float bsv = bias[col];
        #pragma unroll
        for (int r = 0; r < 4; ++r) {
          float v = acc[i][j][r] + bsv;
          if (MODE == 1) ((u16*)Cout)[(size_t)(row + r) * ldc + col] = f2bf(v);
          else           ((float*)Cout)[(size_t)(row + r) * ldc + col] = v;
        }
      }
    }
  }
}

// ======== gemm_bt64: BK=64 variant for gemm2 (R8) + T1 XCD swizzle ========
__global__ __launch_bounds__(256, 3)
void gemm_bt64(const u16* __restrict__ A, const u16* __restrict__ Bt,
               const float* __restrict__ bias, float* __restrict__ Cout,
               int M, int N, int K) {
  __shared__ u16 As[2][128 * 64];
  __shared__ u16 Bs[2][64 * 64];
  const int tid = threadIdx.x;
  const int ln = tid & 63, w = tid >> 6;
  const int wm = w >> 1, wn = w & 1;
  const int l15 = ln & 15, lq = ln >> 4;
  const int swz = l15 & 7;
  const int nbx = gridDim.x;
  const int wg  = xcd_swizzle(blockIdx.y * nbx + blockIdx.x, nbx * gridDim.y);
  const int m0 = (wg / nbx) * 128, n0 = (wg % nbx) * 64;

  int aoff[4], boff[2];
  #pragma unroll
  for (int i = 0; i < 4; ++i) {             // A: 128 rows x 8 chunks = 1024 slots
    int s = i * 256 + tid;
    aoff[i] = (m0 + (s >> 3)) * K + (((s & 7) ^ ((s >> 3) & 7)) * 8);
  }
  #pragma unroll
  for (int i = 0; i < 2; ++i) {             // B: 64 rows x 8 chunks = 512 slots
    int s = i * 256 + tid;
    boff[i] = (n0 + (s >> 3)) * K + (((s & 7) ^ ((s >> 3) & 7)) * 8);
  }

  f32x4 acc[4][2];
  #pragma unroll
  for (int i = 0; i < 4; ++i)
    #pragma unroll
    for (int j = 0; j < 2; ++j) acc[i][j] = (f32x4){0.f, 0.f, 0.f, 0.f};

  const int NK = K >> 6;   // 16

  auto STAGE = [&](int buf, int t) {
    const int k0 = t * 64;
    #pragma unroll
    for (int i = 0; i < 4; ++i)
      gl2lds16(A + aoff[i] + k0, (char*)As[buf] + (size_t)(i * 256 + w * 64) * 16);
    #pragma unroll
    for (int i = 0; i < 2; ++i)
      gl2lds16(Bt + boff[i] + k0, (char*)Bs[buf] + (size_t)(i * 256 + w * 64) * 16);
  };

  STAGE(0, 0);
  int cur = 0;
  for (int it = 0; it < NK; ++it) {
    __syncthreads();                  // tile `it` landed; buf cur^1 readers done
    if (it + 1 < NK) STAGE(cur ^ 1, it + 1);
    const u16* AsB = As[cur];
    const u16* BsB = Bs[cur];
    bf16x8 af[4][2], bfr[2][2];
    #pragma unroll
    for (int i = 0; i < 4; ++i)
      #pragma unroll
      for (int kk = 0; kk < 2; ++kk)
        af[i][kk] = ldb8(&AsB[(wm * 64 + i * 16 + l15) * 64 + (((kk * 4 + lq) ^ swz) * 8)]);
    #pragma unroll
    for (int j = 0; j < 2; ++j)
      #pragma unroll
      for (int kk = 0; kk < 2; ++kk)
        bfr[j][kk] = ldb8(&BsB[(wn * 32 + j * 16 + l15) * 64 + (((kk * 4 + lq) ^ swz) * 8)]);
    __builtin_amdgcn_s_setprio(1);
    #pragma unroll
    for (int i = 0; i < 4; ++i)
      #pragma unroll
      for (int j = 0; j < 2; ++j)
        #pragma unroll
        for (int kk = 0; kk < 2; ++kk)
          acc[i][j] = __builtin_amdgcn_mfma_f32_16x16x32_bf16(af[i][kk], bfr[j][kk], acc[i][j], 0, 0, 0);
    __builtin_amdgcn_s_setprio(0);
    cur ^= 1;
  }

  #pragma unroll
  for (int i = 0; i < 4; ++i) {
    int row = m0 + wm * 64 + i * 16 + lq * 4;
    #pragma unroll
    for (int j = 0; j < 2; ++j) {
      int col = n0 + wn * 32 + j * 16 + l15;
      float bsv = bias[col];
      #pragma unroll
      for (int r = 0; r < 4; ++r)
        Cout[(size_t)(row + r) * N + col] = acc[i][j][r] + bsv;
    }
  }
}

// ===== fused causal flash attention — KVBLK=128, T15 double-pipeline =====
// Round-11: software-pipeline the iteration. Per iter: {issue V(it+1)/K(it+2)
// stages; QK(it+1)->sB (ds_read+MFMA stream); softmax(sA)+PV(it) (VALU+MFMA
// stream); sA<-sB; __syncthreads}. The two streams are register-independent
// so the QK chain overlaps the softmax serial chain (T15, +8-11% measured on
// attn-shaped kernels). Buffers: K triple (QK reads it+1 while it+2 stages;
// WAR on buf (it+2)%3 separated by 2 barriers), V double (V(it) read this
// iter; V-stage targets buf (it+1)%2 whose reader ran last iter, 1 barrier).
// LDS 3*16+2*16 = 80KB -> still 2 blocks/CU. One barrier/iter (unchanged).
__device__ __forceinline__ bf16x8 packp(const f32x4& a, const f32x4& b) {
  bf16x8 r;
  #pragma unroll
  for (int i = 0; i < 4; ++i) { r[i] = (__bf16)a[i]; r[i + 4] = (__bf16)b[i]; }
  return r;
}
__device__ __forceinline__ bf16x8 qscale(const u16* p) {
  u16x8 q = *(const u16x8*)p;
  u16x8 s;
  #pragma unroll
  for (int j = 0; j < 8; ++j) s[j] = f2bf(bf2f(q[j]) * SCALE2);
  return __builtin_bit_cast(bf16x8, s);
}

__global__ __launch_bounds__(256, 2)
void attn_fused(const u16* __restrict__ qk, const u16* __restrict__ vt,
                u16* __restrict__ y) {
  __shared__ u16 Ks[3][128 * 64];   // swizzled [kv-row][d], TRIPLE-buffered
  __shared__ u16 Vts[2][64 * 128];  // swizzled [d-row][kv-permuted], double
  const int tid = threadIdx.x;
  const int ln = tid & 63, w = tid >> 6;
  const int l15 = ln & 15, lq = ln >> 4;
  const int swzK = l15 & 7;
  const int bx = blockIdx.x;
  const int bh = bx & 31;
  const int h  = bh & 15, b = bh >> 4;
  const int rr_ = bx >> 8, g = (bx >> 5) & 7;
  const int qt = (rr_ == 0) ? 31 - g : (rr_ == 1) ? 16 + g : (rr_ == 2) ? 15 - g : g;
  const int q0w = qt * 64 + w * 16;

  const u16* qbase = qk + (size_t)(b * Tt) * 2048 + h * HD;
  const u16* kbase = qk + (size_t)(b * Tt) * 2048 + 1024 + h * HD;
  const u16* vbase = vt + (size_t)(b * 1024 + h * HD) * Tt;

  int koff[4], voff[4];
  #pragma unroll
  for (int i = 0; i < 4; ++i) {
    int s = i * 256 + tid;
    koff[i] = (s >> 3) * 2048 + (((s & 7) ^ ((s >> 3) & 7)) * 8);
    voff[i] = (s >> 4) * Tt + (((s & 15) ^ ((s >> 4) & 15)) * 8);
  }

  const u16* qrA = qbase + (size_t)(q0w + l15) * 2048;
  bf16x8 qA0 = qscale(qrA + lq * 8), qA1 = qscale(qrA + 32 + lq * 8);

  bf16x8 ones;
  #pragma unroll
  for (int j = 0; j < 8; ++j) ones[j] = (__bf16)1.0f;

  f32x4 o[4];
  #pragma unroll
  for (int j = 0; j < 4; ++j) o[j] = (f32x4){0, 0, 0, 0};
  f32x4 lacc = (f32x4){0, 0, 0, 0};
  float m = -__builtin_inff();
  const int qg = q0w + l15;
  const int nkv = (qt >> 1) + 1;

  auto KSTAGE = [&](int buf, int t) {
    const u16* ks = kbase + (size_t)(t * 128) * 2048;
    #pragma unroll
    for (int i = 0; i < 4; ++i)
      gl2lds16(ks + koff[i], (char*)Ks[buf] + (size_t)(i * 256 + w * 64) * 16);
  };
  auto VSTAGE = [&](int buf, int t) {
    const u16* vs = vbase + t * 128;
    #pragma unroll
    for (int i = 0; i < 4; ++i)
      gl2lds16(vs + voff[i], (char*)Vts[buf] + (size_t)(i * 256 + w * 64) * 16);
  };

  f32x4 sA[8], sB[8];
  auto QK = [&](const u16* KsB, f32x4 (&s)[8]) {
    #pragma unroll
    for (int i = 0; i < 8; ++i) s[i] = (f32x4){0, 0, 0, 0};
    __builtin_amdgcn_s_setprio(1);
    #pragma unroll
    for (int i = 0; i < 8; ++i) {
      bf16x8 kf0 = ldb8(&KsB[(i * 16 + l15) * 64 + ((lq      ^ swzK) * 8)]);
      bf16x8 kf1 = ldb8(&KsB[(i * 16 + l15) * 64 + (((lq + 4) ^ swzK) * 8)]);
      s[i] = __builtin_amdgcn_mfma_f32_16x16x32_bf16(kf0, qA0, s[i], 0, 0, 0);
      s[i] = __builtin_amdgcn_mfma_f32_16x16x32_bf16(kf1, qA1, s[i], 0, 0, 0);
    }
    __builtin_amdgcn_s_setprio(0);
  };

  // prologue: K0,V0,K1 staged; S(0) computed
  KSTAGE(0, 0);
  VSTAGE(0, 0);
  if (nkv > 1) KSTAGE(1, 1);
  __syncthreads();
  QK(Ks[0], sA);

  for (int it = 0; it < nkv; ++it) {
    const int kk = it * 128;
    // issue next stages (land by next iter's __syncthreads)
    if (it + 1 < nkv) VSTAGE((it + 1) & 1, it + 1);
    if (it + 2 < nkv) KSTAGE((it + 2) % 3, it + 2);
    // stream 1: QK for tile it+1 (K(it+1) landed at the previous barrier)
    if (it + 1 < nkv) QK(Ks[(it + 1) % 3], sB);

    // stream 2: softmax(sA) for tile it
    if (it == nkv - 1) {
      #pragma unroll
      for (int i = 0; i < 8; ++i)
        #pragma unroll
        for (int r = 0; r < 4; ++r) {
          int kv = kk + i * 16 + lq * 4 + r;
          if (kv > qg) sA[i][r] = -__builtin_inff();
        }
    }
    float a0 = fmaxf(fmaxf(sA[0][0], sA[0][1]), fmaxf(sA[0][2], sA[0][3]));
    float a1 = fmaxf(fmaxf(sA[1][0], sA[1][1]), fmaxf(sA[1][2], sA[1][3]));
    float a2 = fmaxf(fmaxf(sA[2][0], sA[2][1]), fmaxf(sA[2][2], sA[2][3]));
    float a3 = fmaxf(fmaxf(sA[3][0], sA[3][1]), fmaxf(sA[3][2], sA[3][3]));
    float a4 = fmaxf(fmaxf(sA[4][0], sA[4][1]), fmaxf(sA[4][2], sA[4][3]));
    float a5 = fmaxf(fmaxf(sA[5][0], sA[5][1]), fmaxf(sA[5][2], sA[5][3]));
    float a6 = fmaxf(fmaxf(sA[6][0], sA[6][1]), fmaxf(sA[6][2], sA[6][3]));
    float a7 = fmaxf(fmaxf(sA[7][0], sA[7][1]), fmaxf(sA[7][2], sA[7][3]));
    float mx = fmaxf(fmaxf(fmaxf(a0, a1), fmaxf(a2, a3)),
                     fmaxf(fmaxf(a4, a5), fmaxf(a6, a7)));
    mx = fmaxf(mx, __shfl_xor(mx, 16));
#if __has_builtin(__builtin_amdgcn_permlane32_swap)
    {
      unsigned mu = __builtin_bit_cast(unsigned, mx);
      auto r2 = __builtin_amdgcn_permlane32_swap(mu, mu, false, false);
      mx = fmaxf(__builtin_bit_cast(float, (unsigned)r2[0]),
                 __builtin_bit_cast(float, (unsigned)r2[1]));
    }
#else
    mx = fmaxf(mx, __shfl_xor(mx, 32));
#endif

    if (!__all(mx <= m + 8.0f)) {
      float mn = fmaxf(m, mx);
      float al = __builtin_amdgcn_exp2f(m - mn);
      m = mn;
      lacc[0] *= al;
      #pragma unroll
      for (int jd = 0; jd < 4; ++jd)
        #pragma unroll
        for (int r = 0; r < 4; ++r) o[jd][r] *= al;
    }
    #pragma unroll
    for (int i = 0; i < 8; ++i)
      #pragma unroll
      for (int r = 0; r < 4; ++r)
        sA[i][r] = __builtin_amdgcn_exp2f(sA[i][r] - m);

    bf16x8 pk_[4];
    #pragma unroll
    for (int ks = 0; ks < 4; ++ks) pk_[ks] = packp(sA[2 * ks], sA[2 * ks + 1]);

    // PV for tile it (V in buf it&1)
    const u16* VtsB = Vts[it & 1];
    __builtin_amdgcn_s_setprio(1);
    #pragma unroll
    for (int ks = 0; ks < 4; ++ks) {
      lacc = __builtin_amdgcn_mfma_f32_16x16x32_bf16(ones, pk_[ks], lacc, 0, 0, 0);
      #pragma unroll
      for (int jd = 0; jd < 4; ++jd) {
        int d = jd * 16 + l15;
        bf16x8 vf = ldb8(&VtsB[d * 128 + (((ks * 4 + lq) ^ l15) * 8)]);
        o[jd] = __builtin_amdgcn_mfma_f32_16x16x32_bf16(vf, pk_[ks], o[jd], 0, 0, 0);
      }
    }
    __builtin_amdgcn_s_setprio(0);

    // rotate pipeline state
    if (it + 1 < nkv) {
      #pragma unroll
      for (int i = 0; i < 8; ++i) sA[i] = sB[i];
    }
    __syncthreads();   // staged V(it+1)/K(it+2) landed; buffers published
  }

  float inv = 1.f / lacc[0];
  const size_t ybase = (size_t)(b * Tt + q0w + l15) * Cc + h * HD;
  #pragma unroll
  for (int jd = 0; jd < 4; ++jd) {
    u16x4 pk;
    #pragma unroll
    for (int r = 0; r < 4; ++r) pk[r] = f2bf(o[jd][r] * inv);
    *(u16x4*)&y[ybase + jd * 16 + lq * 4] = pk;
  }
}

extern "C" void kernel_launch(void* const* d_in, const int* in_sizes, int n_in,
                              void* d_out, int out_size, void* d_ws, size_t ws_size,
                              hipStream_t stream) {
  const float* x      = (const float*)d_in[0];
  const float* w_attn = (const float*)d_in[1];
  const float* b_attn = (const float*)d_in[2];
  const float* w_proj = (const float*)d_in[3];
  const float* b_proj = (const float*)d_in[4];
  float* out = (float*)d_out;

  char* ws = (char*)d_ws;
  u16* xb  = (u16*)(ws + 0);          // 4096x1024 bf16   (8 MB)
  u16* wat = (u16*)(ws + 8388608);    // 3072x1024 bf16   (6 MB)   w_attn^T
  u16* wpt = (u16*)(ws + 14680064);   // 1024x1024 bf16   (2 MB)   w_proj^T
  u16* qkb = (u16*)(ws + 16777216);   // 4096x2048 bf16   (16 MB)  Q,K
  u16* vtb = (u16*)(ws + 33554432);   // 2048x2048 bf16   (8 MB)   V^T (permuted)
  u16* yb  = (u16*)(ws + 41943040);   // 4096x1024 bf16   (8 MB)

  prep_kernel<<<5120, 256, 0, stream>>>(x, w_attn, w_proj, xb, wat, wpt);
  gemm_bt<1, 128, 3><<<dim3(24, 32), 256, 0, stream>>>(xb, wat, b_attn, (void*)qkb, vtb, 4096, 3072, 1024);
  attn_fused<<<1024, 256, 0, stream>>>(qkb, vtb, yb);
  gemm_bt64<<<dim3(16, 32), 256, 0, stream>>>(yb, wpt, b_proj, out, 4096, 1024, 1024);
}